// Round 4
// baseline (18951.868 us; speedup 1.0000x reference)
//
#include <hip/hip_runtime.h>
#include <cstdint>
#include <cstddef>

#define T_STEPS 1024
#define B_SZ    128
#define F_SZ    88
#define H_SZ    1024
#define C_SZ    88

#define N_GATE_WG 128
#define N_FC_WG   3
#define N_WG      (N_GATE_WG + N_FC_WG)
#define BLOCK     256
#define FLAG_STRIDE 16                          // ints -> 64 B per flag line
#define RING      16                            // h ring slots == inv period

typedef __attribute__((ext_vector_type(8)))  __bf16 bf16x8;
typedef __attribute__((ext_vector_type(16))) float  f32x16;
typedef __attribute__((ext_vector_type(4)))  int    i32x4;

// ---------------- LDS layout (bytes) ----------------
#define SLAB_OFF    0
#define SLAB_BYTES  (70 * 512 * 2)              // 71680
#define BIAS_OFF    (SLAB_OFF + SLAB_BYTES)     // 71680 (32 floats)
#define LENL_OFF    (BIAS_OFF + 128)            // 71808 (128 ints)
#define NB_OFF      (LENL_OFF + 512)            // 72320 (1025 ushort, padded)
#define EXCH_OFF    (NB_OFF + 2064)             // 74384 (16-aligned)
#define EXCH_WAVE   (16 * 68 * 4)               // 4352 B per wave (stride-68 pad)
#define EXCH_BYTES  (4 * EXCH_WAVE)             // 17408
#define STAGE_OFF   (EXCH_OFF + EXCH_BYTES)     // 91792 (16-aligned)
#define STAGE_BYTES (4 * 32 * 8 * 2)            // 2048
#define SMEM_BYTES  (STAGE_OFF + STAGE_BYTES)   // 93840

// one h slot: 64 ktiles * 4 btiles * 64 lanes * 8 bf16
#define HBUF_ELEMS  131072
#define HBUF_BYTES  (HBUF_ELEMS * 2)            // 256 KB per slot, RING slots

__device__ __forceinline__ float sigm(float x) {
    return __builtin_amdgcn_rcpf(1.0f + __expf(-x));
}
__device__ __forceinline__ float tanh_fast(float x) {
    return 1.0f - 2.0f * __builtin_amdgcn_rcpf(__expf(2.0f * x) + 1.0f);
}
// write-through (agent-coherent) 8-byte store: lands at the LLC, bypassing
// the writer's L2 -> consumers' L2-miss fills always see fresh data.
__device__ __forceinline__ void st_llc(void* p, uint64_t v) {
    __hip_atomic_store((uint64_t*)p, v, __ATOMIC_RELAXED,
                       __HIP_MEMORY_SCOPE_AGENT);
}

extern "C" __global__ void __launch_bounds__(BLOCK, 1)
lstm_fused(const float* __restrict__ X,
           const int*   __restrict__ len_raw,
           const float* __restrict__ W_ih,
           const float* __restrict__ W_hh,
           const float* __restrict__ b_ih,
           const float* __restrict__ b_hh,
           const float* __restrict__ W_fc,
           const float* __restrict__ b_fc,
           float*       __restrict__ out,
           __bf16*      __restrict__ hbuf,
           int*         __restrict__ flags)
{
    extern __shared__ char smem[];
    __bf16*         slab  = (__bf16*)(smem + SLAB_OFF);
    float*          biasL = (float*)(smem + BIAS_OFF);
    int*            lenL  = (int*)(smem + LENL_OFF);
    unsigned short* nbL   = (unsigned short*)(smem + NB_OFF);

    const int  wg   = blockIdx.x;
    const int  tid  = threadIdx.x;
    const int  w    = tid >> 6;      // wave = M-tile (batch/32)
    const int  lane = tid & 63;
    const int  col  = lane & 31;
    const int  h5   = lane >> 5;
    const bool isGate = (wg < N_GATE_WG);

    // ---------------- prologue ----------------
    const int lstride = (len_raw[1] == 0) ? 2 : 1;   // int64 vs int32 lengths
    if (tid < B_SZ) lenL[tid] = len_raw[tid * lstride];
    __syncthreads();
    for (int t = tid; t <= T_STEPS; t += BLOCK) {
        int cnt = 0;
        #pragma unroll 4
        for (int b = 0; b < B_SZ; ++b) cnt += (lenL[b] > t) ? 1 : 0;
        nbL[t] = (unsigned short)cnt;
    }

    if (isGate) {
        // wg owns hidden units [j0, j0+8); permuted col = 4*unit_local + gate
        const int j0 = wg * 8;
        for (int idx = tid; idx < 32 * 1024; idx += BLOCK) {
            int cc = idx >> 10, k = idx & 1023;
            int gate = cc & 3, u = cc >> 2;
            float v = W_hh[(size_t)(gate * H_SZ + j0 + u) * H_SZ + k];
            slab[((k >> 4) * 64 + ((k >> 3) & 1) * 32 + cc) * 8 + (k & 7)] = (__bf16)v;
        }
        for (int idx = tid; idx < 32 * 96; idx += BLOCK) {
            int cc = idx & 31, k = idx >> 5;
            int gate = cc & 3, u = cc >> 2;
            float v = (k < F_SZ) ? W_ih[(size_t)(gate * H_SZ + j0 + u) * F_SZ + k] : 0.0f;
            slab[((64 + (k >> 4)) * 64 + ((k >> 3) & 1) * 32 + cc) * 8 + (k & 7)] = (__bf16)v;
        }
        if (tid < 32) {
            int gate = tid & 3, u = tid >> 2;
            int row = gate * H_SZ + j0 + u;
            biasL[tid] = b_ih[row] + b_hh[row];
        }
    } else {
        const int c0 = (wg - N_GATE_WG) * 32;
        for (int idx = tid; idx < 32 * 1024; idx += BLOCK) {
            int cc = idx >> 10, k = idx & 1023;
            int c = c0 + cc;
            float v = (c < C_SZ) ? W_fc[(size_t)c * H_SZ + k] : 0.0f;
            slab[((k >> 4) * 64 + ((k >> 3) & 1) * 32 + cc) * 8 + (k & 7)] = (__bf16)v;
        }
        if (tid < 32) {
            int c = c0 + tid;
            biasL[tid] = (c < C_SZ) ? b_fc[c] : 0.0f;
        }
    }

    __syncthreads();
    if (tid == 0) {
        __builtin_amdgcn_s_waitcnt(0);
        __hip_atomic_store(flags + wg * FLAG_STRIDE, 1, __ATOMIC_RELAXED,
                           __HIP_MEMORY_SCOPE_AGENT);
    }

    // persistent per-lane state: 4 (row,unit) pairs each
    float c_reg[4] = {0.f, 0.f, 0.f, 0.f};
    float h_reg[4] = {0.f, 0.f, 0.f, 0.f};

    const int g4    = col & 3;           // gate index of this lane (i,f,g,o)
    const int ktile = wg >> 1;           // h-buffer k-tile this wg writes
    const int half  = wg & 1;            // which k-half of that tile
    const int u0    = col >> 2;          // unit-local 0..7
    const int c0fc  = (wg - N_GATE_WG) * 32;
    const bool has2 = (128 + lane) < N_WG;

    float*  exch   = (float*)(smem + EXCH_OFF) + w * (EXCH_WAVE / 4);
    __bf16* stageW = (__bf16*)(smem + STAGE_OFF) + w * 256;

    for (int t = 0; t <= T_STEPS; ++t) {
        const int nb_t   = (t < T_STEPS) ? (int)nbL[t] : 0;
        const int nb_pre = (t > 0) ? (int)nbL[t - 1] : B_SZ;
        const __bf16* hin  = hbuf + (size_t)((t + RING - 1) & (RING - 1)) * HBUF_ELEMS;
        __bf16*       hout = hbuf + (size_t)(t & (RING - 1)) * HBUF_ELEMS;

        const bool gcomp = isGate && (t < T_STEPS) && (w * 32 < nb_t);
        const bool gwrt  = isGate && (t < T_STEPS) && (w * 32 < nb_pre);

        f32x16 acc;

        // ---- pre-barrier: bias + x_t @ W_ih^T (independent of h(t-1)) ----
        if (gcomp) {
            float bv = biasL[col];
            #pragma unroll
            for (int i = 0; i < 16; ++i) acc[i] = bv;
            const float* xrow = X + ((size_t)t * B_SZ + (w * 32 + col)) * F_SZ;
            #pragma unroll
            for (int kt = 0; kt < 6; ++kt) {
                int f0 = kt * 16 + h5 * 8;
                bf16x8 a;
                if (f0 < F_SZ) {
                    float4 lo = *(const float4*)(xrow + f0);
                    float4 hi = *(const float4*)(xrow + f0 + 4);
                    a[0] = (__bf16)lo.x; a[1] = (__bf16)lo.y; a[2] = (__bf16)lo.z; a[3] = (__bf16)lo.w;
                    a[4] = (__bf16)hi.x; a[5] = (__bf16)hi.y; a[6] = (__bf16)hi.z; a[7] = (__bf16)hi.w;
                } else {
                    #pragma unroll
                    for (int j = 0; j < 8; ++j) a[j] = (__bf16)0.0f;
                }
                bf16x8 b = __builtin_bit_cast(bf16x8,
                    *(const i32x4*)(slab + (size_t)(64 + kt) * 512 + lane * 8));
                acc = __builtin_amdgcn_mfma_f32_32x32x16_bf16(a, b, acc, 0, 0, 0);
            }
        }

        // ---- decentralized barrier: wave-local poll, 3 flags per lane ----
        {
            const int target = t + 1;
            long g = 0;
            for (;;) {
                int a = __hip_atomic_load(flags + lane * FLAG_STRIDE,
                                          __ATOMIC_RELAXED, __HIP_MEMORY_SCOPE_AGENT);
                int b = __hip_atomic_load(flags + (64 + lane) * FLAG_STRIDE,
                                          __ATOMIC_RELAXED, __HIP_MEMORY_SCOPE_AGENT);
                int c = has2 ? __hip_atomic_load(flags + (128 + lane) * FLAG_STRIDE,
                                                 __ATOMIC_RELAXED, __HIP_MEMORY_SCOPE_AGENT)
                             : target;
                if (__all((a >= target) && (b >= target) && (c >= target))) break;
                if (++g > 200000000L) break;       // anti-hang bail
            }
        }
        __syncthreads();   // also fences: h loads below cannot be hoisted above

        // ---- periodic acquire (buffer_inv), aligned with ring reuse ----
        if ((t & (RING - 1)) == 0) {
            if (tid == 0)
                __builtin_amdgcn_fence(__ATOMIC_ACQUIRE, "agent");
            __syncthreads();
        }

        // FC wgs arrive early (slack via the deep ring)
        if (!isGate && tid == 0) {
            __hip_atomic_store(flags + wg * FLAG_STRIDE, t + 2, __ATOMIC_RELAXED,
                               __HIP_MEMORY_SCOPE_AGENT);
        }

        // ---- FC head: logits(t-1) from h(t-1), cached dwordx4 loads ----
        if (!isGate && t >= 1) {
            const int  s        = t - 1;
            const int  nb_s     = (int)nbL[s];
            const bool act_tile = (w * 32) < nb_s;
            #pragma unroll
            for (int i = 0; i < 16; ++i) acc[i] = 0.0f;
            if (act_tile) {
                float bv = biasL[col];
                #pragma unroll
                for (int i = 0; i < 16; ++i) acc[i] = bv;
                const __bf16* hA = hin + (size_t)(w * 64 + lane) * 8;
                const __bf16* bB = slab + lane * 8;
                #pragma unroll 8
                for (int kt = 0; kt < 64; ++kt) {
                    bf16x8 a = __builtin_bit_cast(bf16x8, *(const i32x4*)(hA + (size_t)kt * 2048));
                    bf16x8 b = __builtin_bit_cast(bf16x8, *(const i32x4*)(bB + (size_t)kt * 512));
                    acc = __builtin_amdgcn_mfma_f32_32x32x16_bf16(a, b, acc, 0, 0, 0);
                }
            }
            const int c = c0fc + col;
            if (c < C_SZ) {
                #pragma unroll
                for (int i = 0; i < 16; ++i) {
                    int row = (i & 3) + 8 * (i >> 2) + 4 * h5;
                    int b   = w * 32 + row;
                    float v = (act_tile && b < nb_s) ? acc[i] : 0.0f;
                    float2 o2; o2.x = v; o2.y = 1.0f - v;
                    *(float2*)(out + ((size_t)(b * T_STEPS + s) * C_SZ + c) * 2) = o2;
                }
            }
        }

        // ---- gate phase 1: h(t-1) @ W_hh^T, cached loads, 4-chunk pipeline ----
        if (gcomp && t > 0) {
            const __bf16* hA = hin + (size_t)(w * 64 + lane) * 8;
            const __bf16* bB = slab + lane * 8;
            i32x4 pf0[16], pf1[16];
            #pragma unroll
            for (int i = 0; i < 16; ++i)
                pf0[i] = *(const i32x4*)(hA + (size_t)i * 2048);
            #pragma unroll
            for (int c = 0; c < 4; ++c) {
                i32x4 (&cur)[16] = (c & 1) ? pf1 : pf0;
                i32x4 (&nxt)[16] = (c & 1) ? pf0 : pf1;
                if (c < 3) {
                    #pragma unroll
                    for (int i = 0; i < 16; ++i)
                        nxt[i] = *(const i32x4*)(hA + (size_t)((c + 1) * 16 + i) * 2048);
                }
                #pragma unroll
                for (int i = 0; i < 16; ++i) {
                    bf16x8 a = __builtin_bit_cast(bf16x8, cur[i]);
                    bf16x8 b = __builtin_bit_cast(bf16x8,
                        *(const i32x4*)(bB + (size_t)(c * 16 + i) * 512));
                    acc = __builtin_amdgcn_mfma_f32_32x32x16_bf16(a, b, acc, 0, 0, 0);
                }
            }
        }
        if (gcomp) {
            #pragma unroll
            for (int j = 0; j < 16; ++j) exch[j * 68 + lane] = acc[j];
        }
        __syncthreads();

        // ---- gate phase 2: activations + state update + h staging ----
        if (gcomp) {
            #pragma unroll
            for (int q = 0; q < 4; ++q) {
                const float4 v = *(const float4*)(exch + (4 * g4 + q) * 68 + 32 * h5 + (col & ~3));
                float si = sigm(v.x);
                float sf = sigm(v.y);
                float tg = tanh_fast(v.z);
                float so = sigm(v.w);
                float cn = sf * c_reg[q] + si * tg;
                float hn = so * tanh_fast(cn);
                int row = 8 * g4 + 4 * h5 + q;
                int b   = w * 32 + row;
                if (b < nb_t) { c_reg[q] = cn; h_reg[q] = hn; }
            }
        }
        if (gwrt) {
            #pragma unroll
            for (int q = 0; q < 4; ++q) {
                int row = 8 * g4 + 4 * h5 + q;
                stageW[row * 8 + u0] = (__bf16)h_reg[q];
            }
        }
        __syncthreads();

        // ---- gate phase 3: write-through blocked store of h(t) to LLC ----
        if (gwrt && h5 == half) {
            const uint64_t* sp = (const uint64_t*)(stageW + col * 8);
            uint64_t* hp = (uint64_t*)(hout + (size_t)((ktile * 4 + w) * 64 + half * 32 + col) * 8);
            st_llc(hp,     sp[0]);
            st_llc(hp + 1, sp[1]);
        }
        __syncthreads();   // per-wave vmcnt(0) drain: h(t) is at the LLC after this

        if (isGate && tid == 0) {
            __builtin_amdgcn_s_waitcnt(0);
            __hip_atomic_store(flags + wg * FLAG_STRIDE, t + 2, __ATOMIC_RELAXED,
                               __HIP_MEMORY_SCOPE_AGENT);
        }
    }
}

extern "C" void kernel_launch(void* const* d_in, const int* in_sizes, int n_in,
                              void* d_out, int out_size, void* d_ws, size_t ws_size,
                              hipStream_t stream) {
    const float* X    = (const float*)d_in[0];
    const int*   lens = (const int*)d_in[1];
    const float* Wih  = (const float*)d_in[2];
    const float* Whh  = (const float*)d_in[3];
    const float* bih  = (const float*)d_in[4];
    const float* bhh  = (const float*)d_in[5];
    const float* Wfc  = (const float*)d_in[6];
    const float* bfc  = (const float*)d_in[7];
    float*       outp = (float*)d_out;

    __bf16* hbuf  = (__bf16*)d_ws;                                 // RING x 256 KB
    int*    flags = (int*)((char*)d_ws + (size_t)RING * HBUF_BYTES);

    (void)hipFuncSetAttribute((const void*)lstm_fused,
                              hipFuncAttributeMaxDynamicSharedMemorySize, SMEM_BYTES);

    void* args[] = { (void*)&X, (void*)&lens, (void*)&Wih, (void*)&Whh,
                     (void*)&bih, (void*)&bhh, (void*)&Wfc, (void*)&bfc,
                     (void*)&outp, (void*)&hbuf, (void*)&flags };
    (void)hipLaunchCooperativeKernel((void*)lstm_fused, dim3(N_WG), dim3(BLOCK),
                                     args, (unsigned)SMEM_BYTES, stream);
}

// Round 5
// 8376.514 us; speedup vs baseline: 2.2625x; 2.2625x over previous
//
#include <hip/hip_runtime.h>
#include <cstdint>
#include <cstddef>

#define T_STEPS 1024
#define B_SZ    128
#define F_SZ    88
#define H_SZ    1024
#define C_SZ    88

#define N_GATE_WG 128
#define N_FC_WG   3
#define N_COMPUTE (N_GATE_WG + N_FC_WG)         // 131
#define N_WG      (N_COMPUTE + 1)               // +1 dedicated barrier master
#define BLOCK     256
#define FLAG_STRIDE 16                          // ints -> 64 B per flag line
#define RING      16                            // h ring slots == inv period

typedef __attribute__((ext_vector_type(8)))  __bf16 bf16x8;
typedef __attribute__((ext_vector_type(16))) float  f32x16;
typedef __attribute__((ext_vector_type(4)))  int    i32x4;

// ---------------- LDS layout (bytes) ----------------
#define SLAB_OFF    0
#define SLAB_BYTES  (70 * 512 * 2)              // 71680
#define BIAS_OFF    (SLAB_OFF + SLAB_BYTES)     // 71680 (32 floats)
#define LENL_OFF    (BIAS_OFF + 128)            // 71808 (128 ints)
#define NB_OFF      (LENL_OFF + 512)            // 72320 (1025 ushort, padded)
#define EXCH_OFF    (NB_OFF + 2064)             // 74384 (16-aligned)
#define EXCH_WAVE   (16 * 68 * 4)               // 4352 B per wave (stride-68 pad)
#define EXCH_BYTES  (4 * EXCH_WAVE)             // 17408
#define STAGE_OFF   (EXCH_OFF + EXCH_BYTES)     // 91792 (16-aligned)
#define STAGE_BYTES (4 * 32 * 8 * 2)            // 2048
#define SMEM_BYTES  (STAGE_OFF + STAGE_BYTES)   // 93840

// one h slot: 64 ktiles * 4 btiles * 64 lanes * 8 bf16
#define HBUF_ELEMS  131072
#define HBUF_BYTES  (HBUF_ELEMS * 2)            // 256 KB per slot, RING slots

#define BCAST_IDX   (136 * FLAG_STRIDE)         // broadcast word, own line

__device__ __forceinline__ float sigm(float x) {
    return __builtin_amdgcn_rcpf(1.0f + __expf(-x));
}
__device__ __forceinline__ float tanh_fast(float x) {
    return 1.0f - 2.0f * __builtin_amdgcn_rcpf(__expf(2.0f * x) + 1.0f);
}
// write-through (agent-coherent) 8-byte store: lands at the LLC, bypassing
// the writer's L2 -> consumers' L2-miss fills always see fresh data.
__device__ __forceinline__ void st_llc(void* p, uint64_t v) {
    __hip_atomic_store((uint64_t*)p, v, __ATOMIC_RELAXED,
                       __HIP_MEMORY_SCOPE_AGENT);
}

extern "C" __global__ void __launch_bounds__(BLOCK, 1)
lstm_fused(const float* __restrict__ X,
           const int*   __restrict__ len_raw,
           const float* __restrict__ W_ih,
           const float* __restrict__ W_hh,
           const float* __restrict__ b_ih,
           const float* __restrict__ b_hh,
           const float* __restrict__ W_fc,
           const float* __restrict__ b_fc,
           float*       __restrict__ out,
           __bf16*      __restrict__ hbuf,
           int*         __restrict__ flags)
{
    extern __shared__ char smem[];
    __bf16*         slab  = (__bf16*)(smem + SLAB_OFF);
    float*          biasL = (float*)(smem + BIAS_OFF);
    int*            lenL  = (int*)(smem + LENL_OFF);
    unsigned short* nbL   = (unsigned short*)(smem + NB_OFF);

    const int  wg   = blockIdx.x;
    const int  tid  = threadIdx.x;
    const int  w    = tid >> 6;      // wave = M-tile (batch/32)
    const int  lane = tid & 63;
    const int  col  = lane & 31;
    const int  h5   = lane >> 5;
    const bool isGate   = (wg < N_GATE_WG);
    const bool isMaster = (wg == N_COMPUTE);

    // ---------------- prologue ----------------
    const int lstride = (len_raw[1] == 0) ? 2 : 1;   // int64 vs int32 lengths
    if (tid < B_SZ) lenL[tid] = len_raw[tid * lstride];
    __syncthreads();
    for (int t = tid; t <= T_STEPS; t += BLOCK) {
        int cnt = 0;
        #pragma unroll 4
        for (int b = 0; b < B_SZ; ++b) cnt += (lenL[b] > t) ? 1 : 0;
        nbL[t] = (unsigned short)cnt;
    }

    if (isGate) {
        // wg owns hidden units [j0, j0+8); permuted col = 4*unit_local + gate
        const int j0 = wg * 8;
        for (int idx = tid; idx < 32 * 1024; idx += BLOCK) {
            int cc = idx >> 10, k = idx & 1023;
            int gate = cc & 3, u = cc >> 2;
            float v = W_hh[(size_t)(gate * H_SZ + j0 + u) * H_SZ + k];
            slab[((k >> 4) * 64 + ((k >> 3) & 1) * 32 + cc) * 8 + (k & 7)] = (__bf16)v;
        }
        for (int idx = tid; idx < 32 * 96; idx += BLOCK) {
            int cc = idx & 31, k = idx >> 5;
            int gate = cc & 3, u = cc >> 2;
            float v = (k < F_SZ) ? W_ih[(size_t)(gate * H_SZ + j0 + u) * F_SZ + k] : 0.0f;
            slab[((64 + (k >> 4)) * 64 + ((k >> 3) & 1) * 32 + cc) * 8 + (k & 7)] = (__bf16)v;
        }
        if (tid < 32) {
            int gate = tid & 3, u = tid >> 2;
            int row = gate * H_SZ + j0 + u;
            biasL[tid] = b_ih[row] + b_hh[row];
        }
    } else if (!isMaster) {
        const int c0 = (wg - N_GATE_WG) * 32;
        for (int idx = tid; idx < 32 * 1024; idx += BLOCK) {
            int cc = idx >> 10, k = idx & 1023;
            int c = c0 + cc;
            float v = (c < C_SZ) ? W_fc[(size_t)c * H_SZ + k] : 0.0f;
            slab[((k >> 4) * 64 + ((k >> 3) & 1) * 32 + cc) * 8 + (k & 7)] = (__bf16)v;
        }
        if (tid < 32) {
            int c = c0 + tid;
            biasL[tid] = (c < C_SZ) ? b_fc[c] : 0.0f;
        }
    }

    __syncthreads();
    if (tid == 0 && !isMaster) {
        __builtin_amdgcn_s_waitcnt(0);
        __hip_atomic_store(flags + wg * FLAG_STRIDE, 1, __ATOMIC_RELAXED,
                           __HIP_MEMORY_SCOPE_AGENT);
    }

    // ---------------- dedicated barrier master ----------------
    if (isMaster) {
        if (w != 0) return;                      // waves 1-3 idle out
        const bool has2 = (128 + lane) < N_COMPUTE;
        long g = 0;
        for (int t = 0; t <= T_STEPS; ++t) {
            const int target = t + 1;
            for (;;) {
                int a = __hip_atomic_load(flags + lane * FLAG_STRIDE,
                                          __ATOMIC_RELAXED, __HIP_MEMORY_SCOPE_AGENT);
                int b = __hip_atomic_load(flags + (64 + lane) * FLAG_STRIDE,
                                          __ATOMIC_RELAXED, __HIP_MEMORY_SCOPE_AGENT);
                int c = has2 ? __hip_atomic_load(flags + (128 + lane) * FLAG_STRIDE,
                                                 __ATOMIC_RELAXED, __HIP_MEMORY_SCOPE_AGENT)
                             : target;
                if (__all((a >= target) && (b >= target) && (c >= target))) break;
                __builtin_amdgcn_s_sleep(1);
                if (++g > 400000000L) break;     // anti-hang bail
            }
            if (lane == 0)
                __hip_atomic_store(flags + BCAST_IDX, target, __ATOMIC_RELAXED,
                                   __HIP_MEMORY_SCOPE_AGENT);
        }
        return;
    }

    // persistent per-lane state: 4 (row,unit) pairs each
    float c_reg[4] = {0.f, 0.f, 0.f, 0.f};
    float h_reg[4] = {0.f, 0.f, 0.f, 0.f};

    const int g4    = col & 3;           // gate index of this lane (i,f,g,o)
    const int ktile = wg >> 1;           // h-buffer k-tile this wg writes
    const int half  = wg & 1;            // which k-half of that tile
    const int u0    = col >> 2;          // unit-local 0..7
    const int c0fc  = (wg - N_GATE_WG) * 32;
    const int phase = wg & (RING - 1);   // staggered-inv phase

    float*  exch   = (float*)(smem + EXCH_OFF) + w * (EXCH_WAVE / 4);
    __bf16* stageW = (__bf16*)(smem + STAGE_OFF) + w * 256;

    long guard = 0;

    for (int t = 0; t <= T_STEPS; ++t) {
        const int nb_t   = (t < T_STEPS) ? (int)nbL[t] : 0;
        const int nb_pre = (t > 0) ? (int)nbL[t - 1] : B_SZ;
        const __bf16* hin  = hbuf + (size_t)((t + RING - 1) & (RING - 1)) * HBUF_ELEMS;
        __bf16*       hout = hbuf + (size_t)(t & (RING - 1)) * HBUF_ELEMS;

        const bool gcomp = isGate && (t < T_STEPS) && (w * 32 < nb_t);
        const bool gwrt  = isGate && (t < T_STEPS) && (w * 32 < nb_pre);

        f32x16 acc;

        // ---- pre-barrier: bias + x_t @ W_ih^T (independent of h(t-1)) ----
        if (gcomp) {
            float bv = biasL[col];
            #pragma unroll
            for (int i = 0; i < 16; ++i) acc[i] = bv;
            const float* xrow = X + ((size_t)t * B_SZ + (w * 32 + col)) * F_SZ;
            #pragma unroll
            for (int kt = 0; kt < 6; ++kt) {
                int f0 = kt * 16 + h5 * 8;
                bf16x8 a;
                if (f0 < F_SZ) {
                    float4 lo = *(const float4*)(xrow + f0);
                    float4 hi = *(const float4*)(xrow + f0 + 4);
                    a[0] = (__bf16)lo.x; a[1] = (__bf16)lo.y; a[2] = (__bf16)lo.z; a[3] = (__bf16)lo.w;
                    a[4] = (__bf16)hi.x; a[5] = (__bf16)hi.y; a[6] = (__bf16)hi.z; a[7] = (__bf16)hi.w;
                } else {
                    #pragma unroll
                    for (int j = 0; j < 8; ++j) a[j] = (__bf16)0.0f;
                }
                bf16x8 b = __builtin_bit_cast(bf16x8,
                    *(const i32x4*)(slab + (size_t)(64 + kt) * 512 + lane * 8));
                acc = __builtin_amdgcn_mfma_f32_32x32x16_bf16(a, b, acc, 0, 0, 0);
            }
        }

        // ---- barrier: poll the single broadcast word (1 request/wave) ----
        {
            const int target = t + 1;
            for (;;) {
                int v = __hip_atomic_load(flags + BCAST_IDX, __ATOMIC_RELAXED,
                                          __HIP_MEMORY_SCOPE_AGENT);
                if (v >= target) break;
                __builtin_amdgcn_s_sleep(1);
                if (++guard > 400000000L) break;   // anti-hang bail
            }
        }
        __syncthreads();   // all waves saw bcast; h loads can't hoist above

        // ---- staggered periodic acquire (buffer_inv), once per ring window ----
        if (((t + phase) & (RING - 1)) == 0) {
            if (tid == 0)
                __builtin_amdgcn_fence(__ATOMIC_ACQUIRE, "agent");
            __syncthreads();
        }

        // FC wgs arrive early (slack via the deep ring)
        if (!isGate && tid == 0) {
            __hip_atomic_store(flags + wg * FLAG_STRIDE, t + 2, __ATOMIC_RELAXED,
                               __HIP_MEMORY_SCOPE_AGENT);
        }

        // ---- FC head: logits(t-1) from h(t-1), cached dwordx4 loads ----
        if (!isGate && t >= 1) {
            const int  s        = t - 1;
            const int  nb_s     = (int)nbL[s];
            const bool act_tile = (w * 32) < nb_s;
            #pragma unroll
            for (int i = 0; i < 16; ++i) acc[i] = 0.0f;
            if (act_tile) {
                float bv = biasL[col];
                #pragma unroll
                for (int i = 0; i < 16; ++i) acc[i] = bv;
                const __bf16* hA = hin + (size_t)(w * 64 + lane) * 8;
                const __bf16* bB = slab + lane * 8;
                #pragma unroll 8
                for (int kt = 0; kt < 64; ++kt) {
                    bf16x8 a = __builtin_bit_cast(bf16x8, *(const i32x4*)(hA + (size_t)kt * 2048));
                    bf16x8 b = __builtin_bit_cast(bf16x8, *(const i32x4*)(bB + (size_t)kt * 512));
                    acc = __builtin_amdgcn_mfma_f32_32x32x16_bf16(a, b, acc, 0, 0, 0);
                }
            }
            const int c = c0fc + col;
            if (c < C_SZ) {
                #pragma unroll
                for (int i = 0; i < 16; ++i) {
                    int row = (i & 3) + 8 * (i >> 2) + 4 * h5;
                    int b   = w * 32 + row;
                    float v = (act_tile && b < nb_s) ? acc[i] : 0.0f;
                    float2 o2; o2.x = v; o2.y = 1.0f - v;
                    *(float2*)(out + ((size_t)(b * T_STEPS + s) * C_SZ + c) * 2) = o2;
                }
            }
        }

        // ---- gate phase 1: h(t-1) @ W_hh^T, pinned 4-chunk load pipeline ----
        if (gcomp && t > 0) {
            const __bf16* hA = hin + (size_t)(w * 64 + lane) * 8;
            const __bf16* bB = slab + lane * 8;
            i32x4 pf0[16], pf1[16];
            #pragma unroll
            for (int i = 0; i < 16; ++i)
                pf0[i] = *(const i32x4*)(hA + (size_t)i * 2048);
            __builtin_amdgcn_sched_barrier(0);
            #pragma unroll
            for (int c = 0; c < 4; ++c) {
                i32x4 (&cur)[16] = (c & 1) ? pf1 : pf0;
                i32x4 (&nxt)[16] = (c & 1) ? pf0 : pf1;
                if (c < 3) {
                    #pragma unroll
                    for (int i = 0; i < 16; ++i)
                        nxt[i] = *(const i32x4*)(hA + (size_t)((c + 1) * 16 + i) * 2048);
                }
                __builtin_amdgcn_sched_barrier(0);   // keep next-chunk loads above MFMAs
                #pragma unroll
                for (int i = 0; i < 16; ++i) {
                    bf16x8 a = __builtin_bit_cast(bf16x8, cur[i]);
                    bf16x8 b = __builtin_bit_cast(bf16x8,
                        *(const i32x4*)(bB + (size_t)(c * 16 + i) * 512));
                    acc = __builtin_amdgcn_mfma_f32_32x32x16_bf16(a, b, acc, 0, 0, 0);
                }
                __builtin_amdgcn_sched_barrier(0);
            }
        }
        if (gcomp) {
            #pragma unroll
            for (int j = 0; j < 16; ++j) exch[j * 68 + lane] = acc[j];
        }
        __syncthreads();

        // ---- gate phase 2: activations + state update + h staging ----
        if (gcomp) {
            #pragma unroll
            for (int q = 0; q < 4; ++q) {
                const float4 v = *(const float4*)(exch + (4 * g4 + q) * 68 + 32 * h5 + (col & ~3));
                float si = sigm(v.x);
                float sf = sigm(v.y);
                float tg = tanh_fast(v.z);
                float so = sigm(v.w);
                float cn = sf * c_reg[q] + si * tg;
                float hn = so * tanh_fast(cn);
                int row = 8 * g4 + 4 * h5 + q;
                int b   = w * 32 + row;
                if (b < nb_t) { c_reg[q] = cn; h_reg[q] = hn; }
            }
        }
        if (gwrt) {
            #pragma unroll
            for (int q = 0; q < 4; ++q) {
                int row = 8 * g4 + 4 * h5 + q;
                stageW[row * 8 + u0] = (__bf16)h_reg[q];
            }
        }
        __syncthreads();

        // ---- gate phase 3: write-through blocked store of h(t) to LLC ----
        if (gwrt && h5 == half) {
            const uint64_t* sp = (const uint64_t*)(stageW + col * 8);
            uint64_t* hp = (uint64_t*)(hout + (size_t)((ktile * 4 + w) * 64 + half * 32 + col) * 8);
            st_llc(hp,     sp[0]);
            st_llc(hp + 1, sp[1]);
        }
        __syncthreads();   // per-wave vmcnt(0) drain: h(t) is at the LLC after this

        if (isGate && tid == 0) {
            __builtin_amdgcn_s_waitcnt(0);
            __hip_atomic_store(flags + wg * FLAG_STRIDE, t + 2, __ATOMIC_RELAXED,
                               __HIP_MEMORY_SCOPE_AGENT);
        }
    }
}

extern "C" void kernel_launch(void* const* d_in, const int* in_sizes, int n_in,
                              void* d_out, int out_size, void* d_ws, size_t ws_size,
                              hipStream_t stream) {
    const float* X    = (const float*)d_in[0];
    const int*   lens = (const int*)d_in[1];
    const float* Wih  = (const float*)d_in[2];
    const float* Whh  = (const float*)d_in[3];
    const float* bih  = (const float*)d_in[4];
    const float* bhh  = (const float*)d_in[5];
    const float* Wfc  = (const float*)d_in[6];
    const float* bfc  = (const float*)d_in[7];
    float*       outp = (float*)d_out;

    __bf16* hbuf  = (__bf16*)d_ws;                                 // RING x 256 KB
    int*    flags = (int*)((char*)d_ws + (size_t)RING * HBUF_BYTES);

    (void)hipFuncSetAttribute((const void*)lstm_fused,
                              hipFuncAttributeMaxDynamicSharedMemorySize, SMEM_BYTES);

    void* args[] = { (void*)&X, (void*)&lens, (void*)&Wih, (void*)&Whh,
                     (void*)&bih, (void*)&bhh, (void*)&Wfc, (void*)&bfc,
                     (void*)&outp, (void*)&hbuf, (void*)&flags };
    (void)hipLaunchCooperativeKernel((void*)lstm_fused, dim3(N_WG), dim3(BLOCK),
                                     args, (unsigned)SMEM_BYTES, stream);
}